// Round 6
// baseline (17379.706 us; speedup 1.0000x reference)
//
#include <hip/hip_runtime.h>
#include <cstdint>
#include <cstddef>

// ---------------- problem constants ----------------
#define T_STEPS 2048
#define NBATCH  64
#define HID     256
#define NGATE   1024            // 4*HID

// recurrent kernel: 512 threads, 8 waves. wv = lw*2 + kh:
//   kh = wv&1  : K-half (k in [kh*128, kh*128+128))
//   lw = wv>>1 : unit group (64 units, lw*64 .. +64)
// lane l: upper = l>>5, lu = l&31; units u0 = lw*64+lu, u1 = u0+32.
// 4 columns/lane: cx=0: u0+upper*512, cx=1: +256, cx=2: u1+upper*512, cx=3: +256.
// Per column 16 chunks (uint4 = 4 k-pairs) over the K-half:
//   c in [0,10): persistent VGPR (wr[4][10] = 160 regs)
//   c in [10,16): streamed from GLOBAL (L2-resident, 192 KB total/layer)
// h broadcast: 16 wave-uniform ds_read_b128 per wave (its K-half only).
// K-halves combined via 8 KB LDS partial buffer (partner wave = tid^64).
#define REC_LDS_BYTES (8192 + 1024)     // pb 8KB + 2 x 256 f16 h buffers

typedef _Float16 f16x8 __attribute__((ext_vector_type(8)));
typedef _Float16 h2f   __attribute__((ext_vector_type(2)));
typedef float    f32x4 __attribute__((ext_vector_type(4)));

__device__ __forceinline__ unsigned short f2h_bits(float f) {
    _Float16 h = (_Float16)f;
    return __builtin_bit_cast(unsigned short, h);
}
__device__ __forceinline__ float h2f_scalar(unsigned short u) {
    return (float)__builtin_bit_cast(_Float16, u);
}

// fdot2: acc += a.x*b.x + a.y*b.y  (f32 accumulate, v_dot2_f32_f16, full rate)
__device__ __forceinline__ float fdot2u(unsigned int hh, unsigned int ww, float acc) {
#if __has_builtin(__builtin_amdgcn_fdot2)
    return __builtin_amdgcn_fdot2(__builtin_bit_cast(h2f, hh),
                                  __builtin_bit_cast(h2f, ww), acc, false);
#else
    h2f a = __builtin_bit_cast(h2f, hh), b = __builtin_bit_cast(h2f, ww);
    return acc + (float)a.x * (float)b.x + (float)a.y * (float)b.y;
#endif
}

// ---------------- workspace layout (bytes) ----------------
#define OFF_G    ((size_t)0)                    // 131072*1024 fp16 = 268435456 (aliased G0/G1)
#define OFF_Y0   ((size_t)268435456)            // 2048*64*256 fp16 = 67108864
#define OFF_WR0  ((size_t)335544320)            // 40*512*8 f16 = 327680 B (reg weight chunks)
#define OFF_WR1  ((size_t)335872000)
#define OFF_WG0  ((size_t)336199680)            // 24*512*8 f16 = 196608 B (L2-streamed tail)
#define OFF_WG1  ((size_t)336396288)
#define OFF_BS0  ((size_t)336592896)            // 128*1024 fp16 swizzled = 262144 B
#define OFF_BS1  ((size_t)336855040)            // 256*1024 fp16 swizzled = 524288 B
#define WS_NEED  ((size_t)337379328)

// ---------------- weight conversion / swizzle ----------------
// WR[( (cx*10 + c)*512 + slot )*8 + i], c in [0,10)
// WG[( (cx*6 + cc)*512 + slot )*8 + i], c = 10+cc, cc in [0,6)
//   slot = wv*64 + l; kh=wv&1, lw=wv>>1; upper=l>>5, lu=l&31
//   unit = lw*64 + lu + (cx>=2 ? 32 : 0); j = unit + upper*512 + (cx&1)*256
//   k = kh*128 + (c*4 + (i>>1))*2 + (i&1)
__global__ void convert_weights(const float* __restrict__ w_ih0, const float* __restrict__ w_hh0,
                                const float* __restrict__ w_ih1, const float* __restrict__ w_hh1,
                                unsigned short* __restrict__ WR0, unsigned short* __restrict__ WR1,
                                unsigned short* __restrict__ WG0, unsigned short* __restrict__ WG1,
                                unsigned short* __restrict__ BS0, unsigned short* __restrict__ BS1)
{
    int gid = blockIdx.x * blockDim.x + threadIdx.x;
    int gsz = gridDim.x * blockDim.x;
    // WR: 40*512*8 = 163840 u16 per layer
    for (int s = gid; s < 163840; s += gsz) {
        int i = s & 7;
        int t = s >> 3;
        int slot = t & 511;
        int ci = t >> 9;                // 0..39
        int cx = ci / 10, c = ci % 10;
        int l = slot & 63, wv = slot >> 6;
        int kh = wv & 1, lw = wv >> 1;
        int upper = l >> 5, lu = l & 31;
        int unit = lw * 64 + lu + ((cx >= 2) ? 32 : 0);
        int j = unit + upper * 512 + (cx & 1) * 256;
        int k = kh * 128 + (c * 4 + (i >> 1)) * 2 + (i & 1);
        WR0[s] = f2h_bits(w_hh0[k * 1024 + j]);
        WR1[s] = f2h_bits(w_hh1[k * 1024 + j]);
    }
    // WG: 24*512*8 = 98304 u16 per layer
    for (int s = gid; s < 98304; s += gsz) {
        int i = s & 7;
        int t = s >> 3;
        int slot = t & 511;
        int ti = t >> 9;                // 0..23
        int cx = ti / 6, cc = ti % 6;
        int c = 10 + cc;
        int l = slot & 63, wv = slot >> 6;
        int kh = wv & 1, lw = wv >> 1;
        int upper = l >> 5, lu = l & 31;
        int unit = lw * 64 + lu + ((cx >= 2) ? 32 : 0);
        int j = unit + upper * 512 + (cx & 1) * 256;
        int k = kh * 128 + (c * 4 + (i >> 1)) * 2 + (i & 1);
        WG0[s] = f2h_bits(w_hh0[k * 1024 + j]);
        WG1[s] = f2h_bits(w_hh1[k * 1024 + j]);
    }
    // Bswz layer0: K=128 (KB=4): s = ((n16*KB+kb)*64+lane)*8+i
    for (int s = gid; s < 131072; s += gsz) {
        int i = s & 7, lane = (s >> 3) & 63, kb = (s >> 9) & 3, n16 = s >> 11;
        int k = kb * 32 + (lane >> 4) * 8 + i;
        int n = n16 * 16 + (lane & 15);
        BS0[s] = f2h_bits(w_ih0[k * 1024 + n]);
    }
    // Bswz layer1: K=256 (KB=8)
    for (int s = gid; s < 262144; s += gsz) {
        int i = s & 7, lane = (s >> 3) & 63, kb = (s >> 9) & 7, n16 = s >> 12;
        int k = kb * 32 + (lane >> 4) * 8 + i;
        int n = n16 * 16 + (lane & 15);
        BS1[s] = f2h_bits(w_ih1[k * 1024 + n]);
    }
}

// ---------------- input-gate GEMM: G[r][swz(n)] = A[map(r)][:] @ w_ih[:, n] + b[n] ----------------
// r = t*64 + b ; layer0: A = x fp32, row (b*2048 + 2047-t), K=128
//                layer1: A = y0 fp16, row ((2047-t)*64 + b), K=256
// G is stored gate-interleaved: col (gate*256+m) -> m*4+gate so the recurrent
// kernel reads a gate pair with ONE u32 load.
template <int KB, int LAYER>
__global__ __launch_bounds__(256) void gemm_in(const float* __restrict__ A32,
                                               const unsigned short* __restrict__ A16,
                                               const unsigned short* __restrict__ Bsw,
                                               const float* __restrict__ bias,
                                               unsigned short* __restrict__ Gout)
{
    const int lane = threadIdx.x & 63;
    const int wave = threadIdx.x >> 6;
    const int nblk = blockIdx.x & 15;        // 16 n-blocks of 64 cols
    const int rblk = blockIdx.x >> 4;        // 1024 r-blocks of 128 rows
    const int r0 = rblk * 128 + wave * 32;
    const int quad = lane >> 4, ln = lane & 15;

    f32x4 acc[2][4];
#pragma unroll
    for (int q = 0; q < 4; q++) {
        float bv = bias[(nblk * 4 + q) * 16 + ln];
#pragma unroll
        for (int mt = 0; mt < 2; mt++) {
            acc[mt][q][0] = bv; acc[mt][q][1] = bv; acc[mt][q][2] = bv; acc[mt][q][3] = bv;
        }
    }
    const int ar0 = r0 + ln, ar1 = r0 + 16 + ln;
    size_t aoff0, aoff1;
    if (LAYER == 0) {
        aoff0 = ((size_t)(ar0 & 63) * 2048 + (size_t)(2047 - (ar0 >> 6))) * 128;
        aoff1 = ((size_t)(ar1 & 63) * 2048 + (size_t)(2047 - (ar1 >> 6))) * 128;
    } else {
        aoff0 = ((size_t)(2047 - (ar0 >> 6)) * 64 + (size_t)(ar0 & 63)) * 256;
        aoff1 = ((size_t)(2047 - (ar1 >> 6)) * 64 + (size_t)(ar1 & 63)) * 256;
    }
#pragma unroll
    for (int kb = 0; kb < KB; kb++) {
        const int k0 = kb * 32 + quad * 8;
        f16x8 a0, a1;
        if (LAYER == 0) {
            const float* p0 = A32 + aoff0 + k0;
            const float* p1 = A32 + aoff1 + k0;
            float4 fa = *(const float4*)(p0);
            float4 fb = *(const float4*)(p0 + 4);
            float4 fc = *(const float4*)(p1);
            float4 fd = *(const float4*)(p1 + 4);
            a0[0] = (_Float16)fa.x; a0[1] = (_Float16)fa.y; a0[2] = (_Float16)fa.z; a0[3] = (_Float16)fa.w;
            a0[4] = (_Float16)fb.x; a0[5] = (_Float16)fb.y; a0[6] = (_Float16)fb.z; a0[7] = (_Float16)fb.w;
            a1[0] = (_Float16)fc.x; a1[1] = (_Float16)fc.y; a1[2] = (_Float16)fc.z; a1[3] = (_Float16)fc.w;
            a1[4] = (_Float16)fd.x; a1[5] = (_Float16)fd.y; a1[6] = (_Float16)fd.z; a1[7] = (_Float16)fd.w;
        } else {
            a0 = *(const f16x8*)(A16 + aoff0 + k0);
            a1 = *(const f16x8*)(A16 + aoff1 + k0);
        }
#pragma unroll
        for (int q = 0; q < 4; q++) {
            f16x8 bq = *(const f16x8*)(Bsw + (((size_t)(nblk * 4 + q) * KB + kb) * 64 + lane) * 8);
            acc[0][q] = __builtin_amdgcn_mfma_f32_16x16x32_f16(a0, bq, acc[0][q], 0, 0, 0);
            acc[1][q] = __builtin_amdgcn_mfma_f32_16x16x32_f16(a1, bq, acc[1][q], 0, 0, 0);
        }
    }
    // C/D layout: col = lane&15, row = (lane>>4)*4 + reg.  Store gate-interleaved.
#pragma unroll
    for (int mt = 0; mt < 2; mt++)
#pragma unroll
        for (int q = 0; q < 4; q++)
#pragma unroll
            for (int rg = 0; rg < 4; rg++) {
                int row = r0 + mt * 16 + quad * 4 + rg;
                int col = (nblk * 4 + q) * 16 + ln;
                int swz = ((col & 255) << 2) | (col >> 8);
                Gout[(size_t)row * 1024 + swz] = f2h_bits(acc[mt][q][rg]);
            }
}

// ---------------- persistent recurrent kernel: 1 WG per batch element ----------------
// Per step:
//   1. issue next-step G loads + tail weight groups cc=0,1 (global, L2-resident)
//   2. reg phase: c = 0..9: one wave-uniform h chunk + 4 cols x 4 fdot2
//   3. tail phase: c = 10..15: weights from the 2-deep global pipeline
//   4. f32x4 partials -> LDS, barrier, add partner (tid^64, other K-half)
//   5. add G, shfl_xor(32) gate exchange, lane-local epilogue x2 units
//   6. kh==0 & l<32 lanes publish h (2 units) to LDS; barrier
template <int LAYER>
__global__ __launch_bounds__(512, 2) void lstm_rec(const unsigned short* __restrict__ G,
                                                   const unsigned short* __restrict__ WR,
                                                   const unsigned short* __restrict__ WG,
                                                   unsigned short* __restrict__ Y0,
                                                   float* __restrict__ Out)
{
    extern __shared__ char smem[];
    float4* pb = (float4*)smem;                                   // 512 f32x4 = 8 KB
    unsigned short* lds_h0 = (unsigned short*)(smem + 8192);      // 256 f16
    unsigned short* lds_h1 = lds_h0 + 256;                        // 256 f16

    const int b = blockIdx.x;
    const int tid = threadIdx.x;
    const int wv = tid >> 6, l = tid & 63;
    const int kh = wv & 1;
    const int lw = wv >> 1;
    const int upper = l >> 5, lu = l & 31;
    const int u0 = lw * 64 + lu;
    const int u1 = u0 + 32;

    // persistent weight chunks: wr[cx][c], c = 0..9
    uint4 wr[4][10];
#pragma unroll
    for (int cx = 0; cx < 4; ++cx)
#pragma unroll
        for (int c = 0; c < 10; ++c)
            wr[cx][c] = *(const uint4*)(WR + ((size_t)((cx * 10 + c) * 512) + tid) * 8);

    const uint4* WGp = (const uint4*)WG;    // [(cx*6+cc)*512 + tid]

    if (tid < 256) lds_h0[tid] = 0;
    float c0s = 0.f, c1s = 0.f, hp0 = 0.f, hp1 = 0.f;
    __syncthreads();

    // G: gate-interleaved; u32 at (row*512 + u*2 + upper) = (col u+upper*512, col +256)
    const unsigned int* Gb = (const unsigned int*)G + (size_t)b * 512;
    const int gi0 = u0 * 2 + upper, gi1 = u1 * 2 + upper;
    unsigned int gp0 = Gb[gi0];             // t = 0
    unsigned int gp1 = Gb[gi1];

    for (int t = 0; t < T_STEPS; ++t) {
        // next step's G pair (full-step latency cover)
        const int tn = (t + 1 < T_STEPS) ? t + 1 : t;
        unsigned int gp0n = Gb[(size_t)tn * 32768 + gi0];
        unsigned int gp1n = Gb[(size_t)tn * 32768 + gi1];

        // tail-weight pipeline: groups cc=0,1 issued at step start (L2-hit ~200cy,
        // covered by the 10-chunk register phase)
        uint4 tg0[4], tg1[4];
#pragma unroll
        for (int cx = 0; cx < 4; ++cx) tg0[cx] = WGp[(cx * 6 + 0) * 512 + tid];
#pragma unroll
        for (int cx = 0; cx < 4; ++cx) tg1[cx] = WGp[(cx * 6 + 1) * 512 + tid];

        // deferred store of h_{t-1} (retires during the dot phase)
        if (t && kh == 0 && upper == 0) {
            if (LAYER == 0) {
                Y0[((size_t)(t - 1) * 64 + b) * 256 + u0] = f2h_bits(hp0);
                Y0[((size_t)(t - 1) * 64 + b) * 256 + u1] = f2h_bits(hp1);
            } else {
                Out[((size_t)(t - 1) * 64 + b) * 256 + u0] = hp0;
                Out[((size_t)(t - 1) * 64 + b) * 256 + u1] = hp1;
            }
        }

        const uint4* hv4 = (const uint4*)((t & 1) ? lds_h1 : lds_h0);
        float a0 = 0.f, a1 = 0.f, a2 = 0.f, a3 = 0.f;

        // ---- register phase: chunks 0..9 of this K-half ----
#pragma unroll
        for (int c = 0; c < 10; ++c) {
            uint4 h4 = hv4[kh * 16 + c];              // wave-uniform broadcast
            uint4 w;
            w = wr[0][c];
            a0 = fdot2u(h4.x, w.x, a0); a0 = fdot2u(h4.y, w.y, a0);
            a0 = fdot2u(h4.z, w.z, a0); a0 = fdot2u(h4.w, w.w, a0);
            w = wr[1][c];
            a1 = fdot2u(h4.x, w.x, a1); a1 = fdot2u(h4.y, w.y, a1);
            a1 = fdot2u(h4.z, w.z, a1); a1 = fdot2u(h4.w, w.w, a1);
            w = wr[2][c];
            a2 = fdot2u(h4.x, w.x, a2); a2 = fdot2u(h4.y, w.y, a2);
            a2 = fdot2u(h4.z, w.z, a2); a2 = fdot2u(h4.w, w.w, a2);
            w = wr[3][c];
            a3 = fdot2u(h4.x, w.x, a3); a3 = fdot2u(h4.y, w.y, a3);
            a3 = fdot2u(h4.z, w.z, a3); a3 = fdot2u(h4.w, w.w, a3);
        }
        // ---- tail phase: chunks 10..15, weights streamed from L2 ----
#pragma unroll
        for (int cc = 0; cc < 6; ++cc) {
            const int c = 10 + cc;
            uint4 h4 = hv4[kh * 16 + c];
            if ((cc & 1) == 0) {
                uint4 w;
                w = tg0[0];
                a0 = fdot2u(h4.x, w.x, a0); a0 = fdot2u(h4.y, w.y, a0);
                a0 = fdot2u(h4.z, w.z, a0); a0 = fdot2u(h4.w, w.w, a0);
                w = tg0[1];
                a1 = fdot2u(h4.x, w.x, a1); a1 = fdot2u(h4.y, w.y, a1);
                a1 = fdot2u(h4.z, w.z, a1); a1 = fdot2u(h4.w, w.w, a1);
                w = tg0[2];
                a2 = fdot2u(h4.x, w.x, a2); a2 = fdot2u(h4.y, w.y, a2);
                a2 = fdot2u(h4.z, w.z, a2); a2 = fdot2u(h4.w, w.w, a2);
                w = tg0[3];
                a3 = fdot2u(h4.x, w.x, a3); a3 = fdot2u(h4.y, w.y, a3);
                a3 = fdot2u(h4.z, w.z, a3); a3 = fdot2u(h4.w, w.w, a3);
                if (cc + 2 < 6) {
#pragma unroll
                    for (int cx = 0; cx < 4; ++cx)
                        tg0[cx] = WGp[(cx * 6 + cc + 2) * 512 + tid];
                }
            } else {
                uint4 w;
                w = tg1[0];
                a0 = fdot2u(h4.x, w.x, a0); a0 = fdot2u(h4.y, w.y, a0);
                a0 = fdot2u(h4.z, w.z, a0); a0 = fdot2u(h4.w, w.w, a0);
                w = tg1[1];
                a1 = fdot2u(h4.x, w.x, a1); a1 = fdot2u(h4.y, w.y, a1);
                a1 = fdot2u(h4.z, w.z, a1); a1 = fdot2u(h4.w, w.w, a1);
                w = tg1[2];
                a2 = fdot2u(h4.x, w.x, a2); a2 = fdot2u(h4.y, w.y, a2);
                a2 = fdot2u(h4.z, w.z, a2); a2 = fdot2u(h4.w, w.w, a2);
                w = tg1[3];
                a3 = fdot2u(h4.x, w.x, a3); a3 = fdot2u(h4.y, w.y, a3);
                a3 = fdot2u(h4.z, w.z, a3); a3 = fdot2u(h4.w, w.w, a3);
                if (cc + 2 < 6) {
#pragma unroll
                    for (int cx = 0; cx < 4; ++cx)
                        tg1[cx] = WGp[(cx * 6 + cc + 2) * 512 + tid];
                }
            }
        }

        // ---- combine K-halves via LDS (partner = tid ^ 64) ----
        float4 pv; pv.x = a0; pv.y = a1; pv.z = a2; pv.w = a3;
        pb[tid] = pv;
        __syncthreads();
        float4 pp = pb[tid ^ 64];

        float s0 = a0 + pp.x, s1 = a1 + pp.y;
        float s2 = a2 + pp.z, s3 = a3 + pp.w;

        // unit u0
        {
            float v0 = h2f_scalar((unsigned short)(gp0 & 0xffff)) + s0;
            float v1 = h2f_scalar((unsigned short)(gp0 >> 16)) + s1;
            float q0 = __shfl_xor(v0, 32, 64);
            float q1 = __shfl_xor(v1, 32, 64);
            float fg = upper ? q0 : v0;
            float ig = upper ? q1 : v1;
            float og = upper ? v0 : q0;
            float gg = upper ? v1 : q1;
            float sf = 1.f / (1.f + __expf(-fg));
            float si = 1.f / (1.f + __expf(-ig));
            float so = 1.f / (1.f + __expf(-og));
            float tg = 1.f - 2.f / (1.f + __expf(2.f * gg));
            c0s = sf * c0s + si * tg;
            float tc = 1.f - 2.f / (1.f + __expf(2.f * c0s));
            hp0 = so * tc;
        }
        // unit u1
        {
            float v0 = h2f_scalar((unsigned short)(gp1 & 0xffff)) + s2;
            float v1 = h2f_scalar((unsigned short)(gp1 >> 16)) + s3;
            float q0 = __shfl_xor(v0, 32, 64);
            float q1 = __shfl_xor(v1, 32, 64);
            float fg = upper ? q0 : v0;
            float ig = upper ? q1 : v1;
            float og = upper ? v0 : q0;
            float gg = upper ? v1 : q1;
            float sf = 1.f / (1.f + __expf(-fg));
            float si = 1.f / (1.f + __expf(-ig));
            float so = 1.f / (1.f + __expf(-og));
            float tg = 1.f - 2.f / (1.f + __expf(2.f * gg));
            c1s = sf * c1s + si * tg;
            float tc = 1.f - 2.f / (1.f + __expf(2.f * c1s));
            hp1 = so * tc;
        }

        unsigned short* hn = (t & 1) ? lds_h0 : lds_h1;
        if (kh == 0 && upper == 0) {
            hn[u0] = f2h_bits(hp0);
            hn[u1] = f2h_bits(hp1);
        }
        gp0 = gp0n; gp1 = gp1n;
        __syncthreads();
    }
    if (kh == 0 && upper == 0) {
        if (LAYER == 0) {
            Y0[((size_t)(T_STEPS - 1) * 64 + b) * 256 + u0] = f2h_bits(hp0);
            Y0[((size_t)(T_STEPS - 1) * 64 + b) * 256 + u1] = f2h_bits(hp1);
        } else {
            Out[((size_t)(T_STEPS - 1) * 64 + b) * 256 + u0] = hp0;
            Out[((size_t)(T_STEPS - 1) * 64 + b) * 256 + u1] = hp1;
        }
        Out[(size_t)33554432 + (size_t)LAYER * 16384 + (size_t)b * 256 + u0] = hp0;            // hn
        Out[(size_t)33554432 + (size_t)LAYER * 16384 + (size_t)b * 256 + u1] = hp1;
        Out[(size_t)33554432 + 32768 + (size_t)LAYER * 16384 + (size_t)b * 256 + u0] = c0s;    // cn
        Out[(size_t)33554432 + 32768 + (size_t)LAYER * 16384 + (size_t)b * 256 + u1] = c1s;
    }
}

// ---------------- launch ----------------
extern "C" void kernel_launch(void* const* d_in, const int* in_sizes, int n_in,
                              void* d_out, int out_size, void* d_ws, size_t ws_size,
                              hipStream_t stream)
{
    const float* x     = (const float*)d_in[0];
    const float* w_ih0 = (const float*)d_in[1];
    const float* w_hh0 = (const float*)d_in[2];
    const float* b0    = (const float*)d_in[3];
    const float* w_ih1 = (const float*)d_in[4];
    const float* w_hh1 = (const float*)d_in[5];
    const float* b1    = (const float*)d_in[6];
    float* out = (float*)d_out;

    if (ws_size < WS_NEED) return;  // cannot run correctly; fail loudly (output stays poisoned)

    char* ws = (char*)d_ws;
    unsigned short* G   = (unsigned short*)(ws + OFF_G);
    unsigned short* Y0  = (unsigned short*)(ws + OFF_Y0);
    unsigned short* WR0 = (unsigned short*)(ws + OFF_WR0);
    unsigned short* WR1 = (unsigned short*)(ws + OFF_WR1);
    unsigned short* WG0 = (unsigned short*)(ws + OFF_WG0);
    unsigned short* WG1 = (unsigned short*)(ws + OFF_WG1);
    unsigned short* BS0 = (unsigned short*)(ws + OFF_BS0);
    unsigned short* BS1 = (unsigned short*)(ws + OFF_BS1);

    (void)hipFuncSetAttribute(reinterpret_cast<const void*>(&lstm_rec<0>),
                              hipFuncAttributeMaxDynamicSharedMemorySize, REC_LDS_BYTES);
    (void)hipFuncSetAttribute(reinterpret_cast<const void*>(&lstm_rec<1>),
                              hipFuncAttributeMaxDynamicSharedMemorySize, REC_LDS_BYTES);

    convert_weights<<<1024, 256, 0, stream>>>(w_ih0, w_hh0, w_ih1, w_hh1,
                                              WR0, WR1, WG0, WG1, BS0, BS1);
    gemm_in<4, 0><<<16384, 256, 0, stream>>>(x, nullptr, BS0, b0, G);
    lstm_rec<0><<<64, 512, REC_LDS_BYTES, stream>>>(G, WR0, WG0, Y0, out);
    gemm_in<8, 1><<<16384, 256, 0, stream>>>(nullptr, Y0, BS1, b1, G);
    lstm_rec<1><<<64, 512, REC_LDS_BYTES, stream>>>(G, WR1, WG1, Y0, out);
}

// Round 7
// 12029.212 us; speedup vs baseline: 1.4448x; 1.4448x over previous
//
#include <hip/hip_runtime.h>
#include <cstdint>
#include <cstddef>

// ---------------- problem constants ----------------
#define T_STEPS 2048
#define NBATCH  64
#define HID     256
#define NGATE   1024            // 4*HID

// recurrent kernel: 256 threads, 4 waves, __launch_bounds__(256,1) -> 512 unified
// regs/wave. wave wv: kh = wv>>1 (K-half), ug = wv&1 (unit-group base).
// lane (tid): owns 8 columns = 2 units {ug*128+l, ug*128+64+l} x 4 gates over its
// K-half (128 k = 64 pairs = 16 uint4 per col).
//   chunks c 0..11  : persistent registers (96 uint4 = 384 regs, arch+AGPR)
//   chunks c 12..15 : LDS (32 uint4/lane, 128 KB)
// h broadcast: 16 wave-uniform ds_read_b128 per wave (its K-half only).
// K-halves combined via LDS pb (partner tid^128); epilogue split: kh0 lane does
// unit ug*128+l, kh1 lane does ug*128+64+l (all 4 gates lane-local, no shfl).
#define RC 12
#define REC_LDS_BYTES (128*1024 + 8192 + 1024)   // tail 128KB + pb 8KB + 2x256 f16 h

typedef _Float16 f16x8 __attribute__((ext_vector_type(8)));
typedef _Float16 h2f   __attribute__((ext_vector_type(2)));
typedef float    f32x4 __attribute__((ext_vector_type(4)));
typedef unsigned short u16x4 __attribute__((ext_vector_type(4)));

__device__ __forceinline__ unsigned short f2h_bits(float f) {
    _Float16 h = (_Float16)f;
    return __builtin_bit_cast(unsigned short, h);
}
__device__ __forceinline__ float h2f_scalar(unsigned short u) {
    return (float)__builtin_bit_cast(_Float16, u);
}

// fdot2: acc += a.x*b.x + a.y*b.y  (f32 accumulate, v_dot2_f32_f16, full rate)
__device__ __forceinline__ float fdot2u(unsigned int hh, unsigned int ww, float acc) {
#if __has_builtin(__builtin_amdgcn_fdot2)
    return __builtin_amdgcn_fdot2(__builtin_bit_cast(h2f, hh),
                                  __builtin_bit_cast(h2f, ww), acc, false);
#else
    h2f a = __builtin_bit_cast(h2f, hh), b = __builtin_bit_cast(h2f, ww);
    return acc + (float)a.x * (float)b.x + (float)a.y * (float)b.y;
#endif
}

// ---------------- workspace layout (bytes) ----------------
#define OFF_G    ((size_t)0)                    // 131072*1024 fp16 = 268435456 (aliased G0/G1)
#define OFF_Y0   ((size_t)268435456)            // 2048*64*256 fp16 = 67108864
#define OFF_WR0  ((size_t)335544320)            // 96*256*8 f16 = 393216 B (reg weight chunks)
#define OFF_WR1  ((size_t)335937536)
#define OFF_LF0  ((size_t)336330752)            // 32*256*8 f16 = 131072 B (LDS tail chunks)
#define OFF_LF1  ((size_t)336461824)
#define OFF_BS0  ((size_t)336592896)            // 128*1024 fp16 swizzled = 262144 B
#define OFF_BS1  ((size_t)336855040)            // 256*1024 fp16 swizzled = 524288 B
#define WS_NEED  ((size_t)337379328)

// ---------------- weight conversion / swizzle ----------------
// Lane tid: wv=tid>>6, l=tid&63, kh=wv>>1, ug=wv&1.
// Column cx = us*4 + gate (us 0,1): unit = ug*128 + us*64 + l, j = gate*256 + unit.
// Chunk c (uint4, elems i 0..7): k = kh*128 + (c*4 + (i>>1))*2 + (i&1).
// WR[((cx*12 + c)*256 + tid)*8 + i]       c in [0,12)
// LF[((cx*4 + cc)*256 + tid)*8 + i]       c = 12+cc, cc in [0,4)
__global__ void convert_weights(const float* __restrict__ w_ih0, const float* __restrict__ w_hh0,
                                const float* __restrict__ w_ih1, const float* __restrict__ w_hh1,
                                unsigned short* __restrict__ WR0, unsigned short* __restrict__ WR1,
                                unsigned short* __restrict__ LF0, unsigned short* __restrict__ LF1,
                                unsigned short* __restrict__ BS0, unsigned short* __restrict__ BS1)
{
    int gid = blockIdx.x * blockDim.x + threadIdx.x;
    int gsz = gridDim.x * blockDim.x;
    // WR: 96*256*8 = 196608 u16 per layer
    for (int s = gid; s < 196608; s += gsz) {
        int i = s & 7;
        int t = s >> 3;
        int tid = t & 255;
        int ci = t >> 8;                // 0..95
        int c = ci % 12, cx = ci / 12;
        int gate = cx & 3, us = cx >> 2;
        int wv = tid >> 6, l = tid & 63;
        int kh = wv >> 1, ug = wv & 1;
        int unit = ug * 128 + us * 64 + l;
        int j = gate * 256 + unit;
        int k = kh * 128 + (c * 4 + (i >> 1)) * 2 + (i & 1);
        WR0[s] = f2h_bits(w_hh0[k * 1024 + j]);
        WR1[s] = f2h_bits(w_hh1[k * 1024 + j]);
    }
    // LF: 32*256*8 = 65536 u16 per layer
    for (int s = gid; s < 65536; s += gsz) {
        int i = s & 7;
        int t = s >> 3;
        int tid = t & 255;
        int idx = t >> 8;               // 0..31
        int cc = idx & 3, cx = idx >> 2;
        int gate = cx & 3, us = cx >> 2;
        int wv = tid >> 6, l = tid & 63;
        int kh = wv >> 1, ug = wv & 1;
        int unit = ug * 128 + us * 64 + l;
        int j = gate * 256 + unit;
        int k = kh * 128 + ((12 + cc) * 4 + (i >> 1)) * 2 + (i & 1);
        LF0[s] = f2h_bits(w_hh0[k * 1024 + j]);
        LF1[s] = f2h_bits(w_hh1[k * 1024 + j]);
    }
    // Bswz layer0: K=128 (KB=4): s = ((n16*KB+kb)*64+lane)*8+i
    for (int s = gid; s < 131072; s += gsz) {
        int i = s & 7, lane = (s >> 3) & 63, kb = (s >> 9) & 3, n16 = s >> 11;
        int k = kb * 32 + (lane >> 4) * 8 + i;
        int n = n16 * 16 + (lane & 15);
        BS0[s] = f2h_bits(w_ih0[k * 1024 + n]);
    }
    // Bswz layer1: K=256 (KB=8)
    for (int s = gid; s < 262144; s += gsz) {
        int i = s & 7, lane = (s >> 3) & 63, kb = (s >> 9) & 7, n16 = s >> 12;
        int k = kb * 32 + (lane >> 4) * 8 + i;
        int n = n16 * 16 + (lane & 15);
        BS1[s] = f2h_bits(w_ih1[k * 1024 + n]);
    }
}

// ---------------- input-gate GEMM: G[r][swz(n)] = A[map(r)][:] @ w_ih[:, n] + b[n] ----------------
// r = t*64 + b ; layer0: A = x fp32, row (b*2048 + 2047-t), K=128
//                layer1: A = y0 fp16, row ((2047-t)*64 + b), K=256
// G is stored gate-interleaved: col (gate*256+m) -> m*4+gate so the recurrent
// kernel reads all 4 of a unit's gate values with ONE b64 load.
template <int KB, int LAYER>
__global__ __launch_bounds__(256) void gemm_in(const float* __restrict__ A32,
                                               const unsigned short* __restrict__ A16,
                                               const unsigned short* __restrict__ Bsw,
                                               const float* __restrict__ bias,
                                               unsigned short* __restrict__ Gout)
{
    const int lane = threadIdx.x & 63;
    const int wave = threadIdx.x >> 6;
    const int nblk = blockIdx.x & 15;        // 16 n-blocks of 64 cols
    const int rblk = blockIdx.x >> 4;        // 1024 r-blocks of 128 rows
    const int r0 = rblk * 128 + wave * 32;
    const int quad = lane >> 4, ln = lane & 15;

    f32x4 acc[2][4];
#pragma unroll
    for (int q = 0; q < 4; q++) {
        float bv = bias[(nblk * 4 + q) * 16 + ln];
#pragma unroll
        for (int mt = 0; mt < 2; mt++) {
            acc[mt][q][0] = bv; acc[mt][q][1] = bv; acc[mt][q][2] = bv; acc[mt][q][3] = bv;
        }
    }
    const int ar0 = r0 + ln, ar1 = r0 + 16 + ln;
    size_t aoff0, aoff1;
    if (LAYER == 0) {
        aoff0 = ((size_t)(ar0 & 63) * 2048 + (size_t)(2047 - (ar0 >> 6))) * 128;
        aoff1 = ((size_t)(ar1 & 63) * 2048 + (size_t)(2047 - (ar1 >> 6))) * 128;
    } else {
        aoff0 = ((size_t)(2047 - (ar0 >> 6)) * 64 + (size_t)(ar0 & 63)) * 256;
        aoff1 = ((size_t)(2047 - (ar1 >> 6)) * 64 + (size_t)(ar1 & 63)) * 256;
    }
#pragma unroll
    for (int kb = 0; kb < KB; kb++) {
        const int k0 = kb * 32 + quad * 8;
        f16x8 a0, a1;
        if (LAYER == 0) {
            const float* p0 = A32 + aoff0 + k0;
            const float* p1 = A32 + aoff1 + k0;
            float4 fa = *(const float4*)(p0);
            float4 fb = *(const float4*)(p0 + 4);
            float4 fc = *(const float4*)(p1);
            float4 fd = *(const float4*)(p1 + 4);
            a0[0] = (_Float16)fa.x; a0[1] = (_Float16)fa.y; a0[2] = (_Float16)fa.z; a0[3] = (_Float16)fa.w;
            a0[4] = (_Float16)fb.x; a0[5] = (_Float16)fb.y; a0[6] = (_Float16)fb.z; a0[7] = (_Float16)fb.w;
            a1[0] = (_Float16)fc.x; a1[1] = (_Float16)fc.y; a1[2] = (_Float16)fc.z; a1[3] = (_Float16)fc.w;
            a1[4] = (_Float16)fd.x; a1[5] = (_Float16)fd.y; a1[6] = (_Float16)fd.z; a1[7] = (_Float16)fd.w;
        } else {
            a0 = *(const f16x8*)(A16 + aoff0 + k0);
            a1 = *(const f16x8*)(A16 + aoff1 + k0);
        }
#pragma unroll
        for (int q = 0; q < 4; q++) {
            f16x8 bq = *(const f16x8*)(Bsw + (((size_t)(nblk * 4 + q) * KB + kb) * 64 + lane) * 8);
            acc[0][q] = __builtin_amdgcn_mfma_f32_16x16x32_f16(a0, bq, acc[0][q], 0, 0, 0);
            acc[1][q] = __builtin_amdgcn_mfma_f32_16x16x32_f16(a1, bq, acc[1][q], 0, 0, 0);
        }
    }
    // C/D layout: col = lane&15, row = (lane>>4)*4 + reg.  Store gate-interleaved.
#pragma unroll
    for (int mt = 0; mt < 2; mt++)
#pragma unroll
        for (int q = 0; q < 4; q++)
#pragma unroll
            for (int rg = 0; rg < 4; rg++) {
                int row = r0 + mt * 16 + quad * 4 + rg;
                int col = (nblk * 4 + q) * 16 + ln;
                int swz = ((col & 255) << 2) | (col >> 8);
                Gout[(size_t)row * 1024 + swz] = f2h_bits(acc[mt][q][rg]);
            }
}

// ---------------- persistent recurrent kernel: 1 WG (256 thr) per batch element ----------------
// Per step:
//   1. h K-half broadcast: 16 wave-uniform ds_read_b128
//   2. dots: 12 reg chunks + 4 LDS chunks x 8 cols x 4 fdot2
//   3. partials (8 f32) -> pb, barrier, add partner (tid^128, other K-half)
//   4. epilogue for this lane's unit (kh picks which), store y + h; barrier
template <int LAYER>
__global__ __launch_bounds__(256, 1) void lstm_rec(const unsigned short* __restrict__ G,
                                                   const unsigned short* __restrict__ WR,
                                                   const unsigned short* __restrict__ LF,
                                                   unsigned short* __restrict__ Y0,
                                                   float* __restrict__ Out)
{
    extern __shared__ char smem[];
    uint4*  lds_w = (uint4*)smem;                                   // 8192 uint4 = 128 KB
    float4* pb_a  = (float4*)(smem + 131072);                       // 256 x 16B = 4 KB
    float4* pb_b  = (float4*)(smem + 131072 + 4096);                // 4 KB
    unsigned short* lds_h0 = (unsigned short*)(smem + 131072 + 8192);  // 256 f16
    unsigned short* lds_h1 = lds_h0 + 256;                          // 256 f16

    const int b = blockIdx.x;
    const int tid = threadIdx.x;            // 0..255
    const int wv = tid >> 6, l = tid & 63;
    const int kh = wv >> 1;                 // K-half of this wave
    const int ug = wv & 1;                  // unit-group base
    const int mu = ug * 128 + kh * 64 + l;  // this lane's epilogue unit

    // persistent weight chunks: wr[cx][c], cx = us*4+gate, c = 0..11
    uint4 wr[8][RC];
#pragma unroll
    for (int cx = 0; cx < 8; ++cx)
#pragma unroll
        for (int c = 0; c < RC; ++c)
            wr[cx][c] = *(const uint4*)(WR + ((size_t)(cx * RC + c) * 256 + tid) * 8);

    // stage LDS-resident weight tail (chunks 12..15)
    {
        const uint4* src = (const uint4*)LF;
        for (int i = tid; i < 8192; i += 256) lds_w[i] = src[i];
    }
    lds_h0[tid] = 0;
    float c_state = 0.f, hlast = 0.f;
    __syncthreads();

    // G: gate-interleaved; u16x4 at ((t*64+b)*256 + m) = (f,i,o,g) of unit m
    const u16x4* Gp = (const u16x4*)G;
    const size_t gbase = (size_t)b * 256 + mu;
    u16x4 gp = Gp[gbase];                   // t = 0

    for (int t = 0; t < T_STEPS; ++t) {
        // next step's G (full-step latency cover)
        const int tn = (t + 1 < T_STEPS) ? t + 1 : t;
        u16x4 gn = Gp[(size_t)tn * 16384 + gbase];

        const uint4* hv4 = (const uint4*)((t & 1) ? lds_h1 : lds_h0) + kh * 16;

        float a0 = 0.f, a1 = 0.f, a2 = 0.f, a3 = 0.f;
        float a4 = 0.f, a5 = 0.f, a6 = 0.f, a7 = 0.f;

        // ---- register phase: chunks 0..11 of this K-half ----
#pragma unroll
        for (int c = 0; c < RC; ++c) {
            uint4 h4 = hv4[c];                       // wave-uniform broadcast
            uint4 w;
            w = wr[0][c];
            a0 = fdot2u(h4.x, w.x, a0); a0 = fdot2u(h4.y, w.y, a0);
            a0 = fdot2u(h4.z, w.z, a0); a0 = fdot2u(h4.w, w.w, a0);
            w = wr[1][c];
            a1 = fdot2u(h4.x, w.x, a1); a1 = fdot2u(h4.y, w.y, a1);
            a1 = fdot2u(h4.z, w.z, a1); a1 = fdot2u(h4.w, w.w, a1);
            w = wr[2][c];
            a2 = fdot2u(h4.x, w.x, a2); a2 = fdot2u(h4.y, w.y, a2);
            a2 = fdot2u(h4.z, w.z, a2); a2 = fdot2u(h4.w, w.w, a2);
            w = wr[3][c];
            a3 = fdot2u(h4.x, w.x, a3); a3 = fdot2u(h4.y, w.y, a3);
            a3 = fdot2u(h4.z, w.z, a3); a3 = fdot2u(h4.w, w.w, a3);
            w = wr[4][c];
            a4 = fdot2u(h4.x, w.x, a4); a4 = fdot2u(h4.y, w.y, a4);
            a4 = fdot2u(h4.z, w.z, a4); a4 = fdot2u(h4.w, w.w, a4);
            w = wr[5][c];
            a5 = fdot2u(h4.x, w.x, a5); a5 = fdot2u(h4.y, w.y, a5);
            a5 = fdot2u(h4.z, w.z, a5); a5 = fdot2u(h4.w, w.w, a5);
            w = wr[6][c];
            a6 = fdot2u(h4.x, w.x, a6); a6 = fdot2u(h4.y, w.y, a6);
            a6 = fdot2u(h4.z, w.z, a6); a6 = fdot2u(h4.w, w.w, a6);
            w = wr[7][c];
            a7 = fdot2u(h4.x, w.x, a7); a7 = fdot2u(h4.y, w.y, a7);
            a7 = fdot2u(h4.z, w.z, a7); a7 = fdot2u(h4.w, w.w, a7);
        }
        // ---- LDS tail: chunks 12..15 ----
#pragma unroll
        for (int cc = 0; cc < 4; ++cc) {
            uint4 h4 = hv4[RC + cc];
            uint4 w;
            w = lds_w[(0 * 4 + cc) * 256 + tid];
            a0 = fdot2u(h4.x, w.x, a0); a0 = fdot2u(h4.y, w.y, a0);
            a0 = fdot2u(h4.z, w.z, a0); a0 = fdot2u(h4.w, w.w, a0);
            w = lds_w[(1 * 4 + cc) * 256 + tid];
            a1 = fdot2u(h4.x, w.x, a1); a1 = fdot2u(h4.y, w.y, a1);
            a1 = fdot2u(h4.z, w.z, a1); a1 = fdot2u(h4.w, w.w, a1);
            w = lds_w[(2 * 4 + cc) * 256 + tid];
            a2 = fdot2u(h4.x, w.x, a2); a2 = fdot2u(h4.y, w.y, a2);
            a2 = fdot2u(h4.z, w.z, a2); a2 = fdot2u(h4.w, w.w, a2);
            w = lds_w[(3 * 4 + cc) * 256 + tid];
            a3 = fdot2u(h4.x, w.x, a3); a3 = fdot2u(h4.y, w.y, a3);
            a3 = fdot2u(h4.z, w.z, a3); a3 = fdot2u(h4.w, w.w, a3);
            w = lds_w[(4 * 4 + cc) * 256 + tid];
            a4 = fdot2u(h4.x, w.x, a4); a4 = fdot2u(h4.y, w.y, a4);
            a4 = fdot2u(h4.z, w.z, a4); a4 = fdot2u(h4.w, w.w, a4);
            w = lds_w[(5 * 4 + cc) * 256 + tid];
            a5 = fdot2u(h4.x, w.x, a5); a5 = fdot2u(h4.y, w.y, a5);
            a5 = fdot2u(h4.z, w.z, a5); a5 = fdot2u(h4.w, w.w, a5);
            w = lds_w[(6 * 4 + cc) * 256 + tid];
            a6 = fdot2u(h4.x, w.x, a6); a6 = fdot2u(h4.y, w.y, a6);
            a6 = fdot2u(h4.z, w.z, a6); a6 = fdot2u(h4.w, w.w, a6);
            w = lds_w[(7 * 4 + cc) * 256 + tid];
            a7 = fdot2u(h4.x, w.x, a7); a7 = fdot2u(h4.y, w.y, a7);
            a7 = fdot2u(h4.z, w.z, a7); a7 = fdot2u(h4.w, w.w, a7);
        }

        // ---- combine K-halves via LDS (partner = tid ^ 128) ----
        float4 pva; pva.x = a0; pva.y = a1; pva.z = a2; pva.w = a3;
        float4 pvb; pvb.x = a4; pvb.y = a5; pvb.z = a6; pvb.w = a7;
        pb_a[tid] = pva;
        pb_b[tid] = pvb;
        __syncthreads();
        float4 qa = pb_a[tid ^ 128];
        float4 qb = pb_b[tid ^ 128];

        // this lane's unit: us = kh -> acc block a[kh*4 .. kh*4+3]
        float sf_, si_, so_, sg_;
        if (kh == 0) {
            sf_ = a0 + qa.x; si_ = a1 + qa.y; so_ = a2 + qa.z; sg_ = a3 + qa.w;
        } else {
            sf_ = a4 + qb.x; si_ = a5 + qb.y; so_ = a6 + qb.z; sg_ = a7 + qb.w;
        }

        float vf = h2f_scalar(gp[0]) + sf_;
        float vi = h2f_scalar(gp[1]) + si_;
        float vo = h2f_scalar(gp[2]) + so_;
        float vg = h2f_scalar(gp[3]) + sg_;

        float sf = 1.f / (1.f + __expf(-vf));
        float si = 1.f / (1.f + __expf(-vi));
        float so = 1.f / (1.f + __expf(-vo));
        float tg = 1.f - 2.f / (1.f + __expf(2.f * vg));
        c_state = sf * c_state + si * tg;
        float tc = 1.f - 2.f / (1.f + __expf(2.f * c_state));
        float h = so * tc;
        hlast = h;

        // y output + next-step h publish (each unit exactly once across lanes)
        if (LAYER == 0) Y0[((size_t)t * 64 + b) * 256 + mu] = f2h_bits(h);
        else            Out[((size_t)t * 64 + b) * 256 + mu] = h;
        ((t & 1) ? lds_h0 : lds_h1)[mu] = f2h_bits(h);

        gp = gn;
        __syncthreads();
    }
    Out[(size_t)33554432 + (size_t)LAYER * 16384 + (size_t)b * 256 + mu] = hlast;            // hn
    Out[(size_t)33554432 + 32768 + (size_t)LAYER * 16384 + (size_t)b * 256 + mu] = c_state;  // cn
}

// ---------------- launch ----------------
extern "C" void kernel_launch(void* const* d_in, const int* in_sizes, int n_in,
                              void* d_out, int out_size, void* d_ws, size_t ws_size,
                              hipStream_t stream)
{
    const float* x     = (const float*)d_in[0];
    const float* w_ih0 = (const float*)d_in[1];
    const float* w_hh0 = (const float*)d_in[2];
    const float* b0    = (const float*)d_in[3];
    const float* w_ih1 = (const float*)d_in[4];
    const float* w_hh1 = (const float*)d_in[5];
    const float* b1    = (const float*)d_in[6];
    float* out = (float*)d_out;

    if (ws_size < WS_NEED) return;  // cannot run correctly; fail loudly (output stays poisoned)

    char* ws = (char*)d_ws;
    unsigned short* G   = (unsigned short*)(ws + OFF_G);
    unsigned short* Y0  = (unsigned short*)(ws + OFF_Y0);
    unsigned short* WR0 = (unsigned short*)(ws + OFF_WR0);
    unsigned short* WR1 = (unsigned short*)(ws + OFF_WR1);
    unsigned short* LF0 = (unsigned short*)(ws + OFF_LF0);
    unsigned short* LF1 = (unsigned short*)(ws + OFF_LF1);
    unsigned short* BS0 = (unsigned short*)(ws + OFF_BS0);
    unsigned short* BS1 = (unsigned short*)(ws + OFF_BS1);

    (void)hipFuncSetAttribute(reinterpret_cast<const void*>(&lstm_rec<0>),
                              hipFuncAttributeMaxDynamicSharedMemorySize, REC_LDS_BYTES);
    (void)hipFuncSetAttribute(reinterpret_cast<const void*>(&lstm_rec<1>),
                              hipFuncAttributeMaxDynamicSharedMemorySize, REC_LDS_BYTES);

    convert_weights<<<1024, 256, 0, stream>>>(w_ih0, w_hh0, w_ih1, w_hh1,
                                              WR0, WR1, LF0, LF1, BS0, BS1);
    gemm_in<4, 0><<<16384, 256, 0, stream>>>(x, nullptr, BS0, b0, G);
    lstm_rec<0><<<64, 256, REC_LDS_BYTES, stream>>>(G, WR0, LF0, Y0, out);
    gemm_in<8, 1><<<16384, 256, 0, stream>>>(nullptr, Y0, BS1, b1, G);
    lstm_rec<1><<<64, 256, REC_LDS_BYTES, stream>>>(G, WR1, LF1, Y0, out);
}